// Round 1
// baseline (386.874 us; speedup 1.0000x reference)
//
#include <hip/hip_runtime.h>

// Problem constants (from reference)
#define BATCH   64
#define CH      3
#define H_OUT   608
#define W_OUT   608
#define H_IN    416
#define W_IN    416
#define ROW_OFF 85
#define COL_OFF 80

#define W4_OUT  (W_OUT / 4)          // 152 float4 per output row
#define W4_IN   (W_IN / 4)           // 104 float4 per input row
#define PLANE4  (H_OUT * W4_OUT)     // 92416 float4 per (b,c) output plane
#define IPLANE4 (H_IN * W4_IN)       // 43264 float4 per (b,c) input plane

__global__ __launch_bounds__(256)
void composite_kernel(const float4* __restrict__ img,
                      const float4* __restrict__ ref,
                      float4* __restrict__ out)
{
    const int i = blockIdx.x * 256 + threadIdx.x;   // flat float4 index in plane
    const int c = blockIdx.y;
    const int b = blockIdx.z;

    const int y  = i / W4_OUT;            // magic-mul division (const divisor)
    const int x4 = i - y * W4_OUT;

    const float4 r = ref[c * PLANE4 + i];
    float4 o = r;

    const int yy = y - ROW_OFF;
    const int xx = x4 * 4 - COL_OFF;      // multiple of 4 inside window
    if (yy >= 0 && yy < H_IN && xx >= 0 && xx < W_IN) {
        const int base = yy * W4_IN + (xx >> 2);
        const float4 v = img[(b * CH + c) * IPLANE4 + base];
        const float4 m = img[(b * CH + 2) * IPLANE4 + base];  // mask = channel 2
        o.x = (m.x != 0.0f) ? v.x : r.x;
        o.y = (m.y != 0.0f) ? v.y : r.y;
        o.z = (m.z != 0.0f) ? v.z : r.z;
        o.w = (m.w != 0.0f) ? v.w : r.w;
    }

    out[(b * CH + c) * PLANE4 + i] = o;
}

extern "C" void kernel_launch(void* const* d_in, const int* in_sizes, int n_in,
                              void* d_out, int out_size, void* d_ws, size_t ws_size,
                              hipStream_t stream) {
    const float4* img = (const float4*)d_in[0];   // [64,3,416,416] f32
    const float4* ref = (const float4*)d_in[1];   // [1,3,608,608] f32
    float4* out = (float4*)d_out;                 // [64,3,608,608] f32

    dim3 grid(PLANE4 / 256, CH, BATCH);           // 92416/256 = 361 exact
    composite_kernel<<<grid, 256, 0, stream>>>(img, ref, out);
}

// Round 2
// 384.357 us; speedup vs baseline: 1.0065x; 1.0065x over previous
//
#include <hip/hip_runtime.h>

// Problem constants (from reference)
#define BATCH   64
#define CH      3
#define H_OUT   608
#define W_OUT   608
#define H_IN    416
#define W_IN    416
#define ROW_OFF 85
#define COL_OFF 80

#define W4_OUT  (W_OUT / 4)          // 152 float4 per output row
#define W4_IN   (W_IN / 4)           // 104 float4 per input row
#define PLANE4  (H_OUT * W4_OUT)     // 92416 float4 per (b,c) output plane
#define IPLANE4 (H_IN * W4_IN)       // 43264 float4 per (b,c) input plane

#define BCHUNK  4                    // batches per thread

#define SEL(o, m, v, r) \
    o.x = (m.x != 0.0f) ? v.x : r.x; \
    o.y = (m.y != 0.0f) ? v.y : r.y; \
    o.z = (m.z != 0.0f) ? v.z : r.z; \
    o.w = (m.w != 0.0f) ? v.w : r.w;

__global__ __launch_bounds__(256)
void composite_kernel(const float4* __restrict__ img,
                      const float4* __restrict__ ref,
                      float4* __restrict__ out)
{
    const int i  = blockIdx.x * 256 + threadIdx.x;  // float4 position in plane
    const int b0 = blockIdx.y * BCHUNK;

    const int y  = i / W4_OUT;            // magic-mul division (const divisor)
    const int x4 = i - y * W4_OUT;

    // ref is read once per thread (c = 0,1,2), reused across the b-loop
    const float4 r0 = ref[0 * PLANE4 + i];
    const float4 r1 = ref[1 * PLANE4 + i];
    const float4 r2 = ref[2 * PLANE4 + i];

    const int yy = y - ROW_OFF;
    const int xx = x4 * 4 - COL_OFF;      // multiple of 4 inside window
    const bool inw = (yy >= 0 && yy < H_IN && xx >= 0 && xx < W_IN);

    if (inw) {
        const int base = yy * W4_IN + (xx >> 2);
        #pragma unroll
        for (int j = 0; j < BCHUNK; ++j) {
            const int b = b0 + j;
            // mask channel (c=2) doubles as its own value: img read exactly once
            const float4 v0 = img[(b * CH + 0) * IPLANE4 + base];
            const float4 v1 = img[(b * CH + 1) * IPLANE4 + base];
            const float4 m  = img[(b * CH + 2) * IPLANE4 + base];
            float4 o0, o1, o2;
            SEL(o0, m, v0, r0)
            SEL(o1, m, v1, r1)
            SEL(o2, m, m,  r2)
            out[(b * CH + 0) * PLANE4 + i] = o0;
            out[(b * CH + 1) * PLANE4 + i] = o1;
            out[(b * CH + 2) * PLANE4 + i] = o2;
        }
    } else {
        #pragma unroll
        for (int j = 0; j < BCHUNK; ++j) {
            const int b = b0 + j;
            out[(b * CH + 0) * PLANE4 + i] = r0;
            out[(b * CH + 1) * PLANE4 + i] = r1;
            out[(b * CH + 2) * PLANE4 + i] = r2;
        }
    }
}

extern "C" void kernel_launch(void* const* d_in, const int* in_sizes, int n_in,
                              void* d_out, int out_size, void* d_ws, size_t ws_size,
                              hipStream_t stream) {
    const float4* img = (const float4*)d_in[0];   // [64,3,416,416] f32
    const float4* ref = (const float4*)d_in[1];   // [1,3,608,608] f32
    float4* out = (float4*)d_out;                 // [64,3,608,608] f32

    dim3 grid(PLANE4 / 256, BATCH / BCHUNK);      // (361, 16)
    composite_kernel<<<grid, 256, 0, stream>>>(img, ref, out);
}